// Round 11
// baseline (222.489 us; speedup 1.0000x reference)
//
#include <hip/hip_runtime.h>
#include <hip/hip_bf16.h>

// LocalAggregator fused kernel, rev C: full-MFMA (e-phase AND PV), 2 blocks/CU.
//   e-phase (measured rev B, unchanged math): E_k = sum_d (h_i*a_k)[d] * h_j[d]
//     via fp16 16x16x32 MFMA, A-frags register-resident, B from sh_hjh.
//   PV: O = P @ Hj on MFMA with hi/lo-split fp16 Hj (fp32-equivalent accuracy):
//     h = hi16 + lo16;  O += P*hi + P*lo   (fp32 accumulate).
//     P rounded to fp16; denominator l summed from the SAME fp16 p values ->
//     softmax weights renormalize exactly; error is h-quantization ~2^-22 only.
//   P transposes to A-frag layout via a wave-private LDS round trip (no extra
//   barrier: wave w's softmax rows == its PV A rows). sc and 1/l stay in-reg
//   (PV D-frag row index g*4+reg == softmax q).
//   TI=64, 256 threads, grid 512 -> LDS 62 KB -> 2 desynchronized blocks/CU.

typedef _Float16 half8  __attribute__((ext_vector_type(8)));
typedef _Float16 half4v __attribute__((ext_vector_type(4)));
typedef float    f32x4  __attribute__((ext_vector_type(4)));

namespace {
constexpr int kB = 64;
constexpr int kN = 512;
constexpr int kD = 128;
constexpr int TI = 64;          // i-rows per block (4 waves x 16)
constexpr int TJ = 64;          // j-cols per tile
constexpr float kNegInf = -9e15f;
constexpr float kAlpha  = 0.2f;
}

__launch_bounds__(256, 2)
__global__ void gat_mfma_full(const float* __restrict__ hidden,
                              const int*   __restrict__ adj,
                              const float* __restrict__ times,
                              const float* __restrict__ a0,
                              const float* __restrict__ a1,
                              const float* __restrict__ a2,
                              const float* __restrict__ a3,
                              const float* __restrict__ p0p,
                              const float* __restrict__ p1p,
                              float* __restrict__ out)
{
    // Row strides: 136 halves = 272 B and 72 halves = 144 B are both multiples
    // of 16 B (b128-aligned) and give stride 68/36 dwords -> bank 4c mod 32 ->
    // 2-way lane aliasing on column-slice reads = free (m136).
    __shared__ _Float16 sh_hjh  [TJ][136];   // h_j hi, row-major (e-phase B)
    __shared__ _Float16 sh_hjT_hi[kD][72];   // h_j hi, transposed (PV B)
    __shared__ _Float16 sh_hjT_lo[kD][72];   // h_j lo, transposed (PV B)
    __shared__ _Float16 sh_p16 [TI][72];     // fp16 P (PV A, wave-private rows)

    const int t    = threadIdx.x;
    const int b    = blockIdx.x >> 3;
    const int i0   = (blockIdx.x & 7) * TI;
    const int lane = t & 63;
    const int w    = t >> 6;        // wave 0..3, owns i-rows [w*16, w*16+16)
    const int g    = lane >> 4;     // lanegroup 0..3
    const int c    = lane & 15;

    const float p0 = p0p[0];
    const float p1 = p1p[0];

    // ---- build resident e-phase A-frags: af[kc][k] = fp16(h_i[d]*a_k[d]) ----
    // A layout (m89-verified): row = c, k-slot = g*8 + r within 32-chunk kc.
    half8 af[4][4];
    {
        const int arow = i0 + w * 16 + c;
        const float* hrow = hidden + ((size_t)b * kN + arow) * kD;
        const float te = p0 * __expf(-times[(size_t)b * kN + arow]) + p1;
#pragma unroll
        for (int kc = 0; kc < 4; ++kc) {
            const int d0 = kc * 32 + g * 8;
            f32x4 h0 = *reinterpret_cast<const f32x4*>(hrow + d0);
            f32x4 h1 = *reinterpret_cast<const f32x4*>(hrow + d0 + 4);
            if (d0 + 7 == 127) h1[3] = te;
            const float hv[8] = {h0[0], h0[1], h0[2], h0[3],
                                 h1[0], h1[1], h1[2], h1[3]};
            const float* aks[4] = {a0, a1, a2, a3};
#pragma unroll
            for (int k = 0; k < 4; ++k) {
                f32x4 A0 = *reinterpret_cast<const f32x4*>(aks[k] + d0);
                f32x4 A1 = *reinterpret_cast<const f32x4*>(aks[k] + d0 + 4);
                const float av[8] = {A0[0], A0[1], A0[2], A0[3],
                                     A1[0], A1[1], A1[2], A1[3]};
                half8 v;
#pragma unroll
                for (int r = 0; r < 8; ++r) v[r] = (_Float16)(hv[r] * av[r]);
                af[kc][k] = v;
            }
        }
    }

    float m_r[4], l_r[4];
#pragma unroll
    for (int q = 0; q < 4; ++q) { m_r[q] = kNegInf; l_r[q] = 0.f; }
    f32x4 o_acc[8];                 // [nt]: rows q (=D reg), col d = nt*16+c
#pragma unroll
    for (int nt = 0; nt < 8; ++nt) o_acc[nt] = (f32x4)0.f;

    for (int jt = 0; jt < 8; ++jt) {
        __syncthreads();   // prev e/PV done reading sh_hj* -> safe to restage

        // ---- stage h_j tile: row-major hi + transposed hi/lo, patch d=127 ----
#pragma unroll
        for (int it = 0; it < 8; ++it) {
            const int flat = t + it * 256;
            const int row  = flat >> 5;          // 0..63 (local j)
            const int c4   = flat & 31;
            const size_t jrow = (size_t)b * kN + jt * TJ + row;
            f32x4 v = *reinterpret_cast<const f32x4*>(hidden + jrow * kD + c4 * 4);
            if (c4 == 31) v[3] = p0 * __expf(-times[jrow]) + p1;
            half4v hv, lv;
#pragma unroll
            for (int x = 0; x < 4; ++x) {
                _Float16 h = (_Float16)v[x];
                hv[x] = h;
                lv[x] = (_Float16)(v[x] - (float)h);
            }
            *reinterpret_cast<half4v*>(&sh_hjh[row][c4 * 4]) = hv;
            const int d0 = c4 * 4;
#pragma unroll
            for (int x = 0; x < 4; ++x) {
                sh_hjT_hi[d0 + x][row] = hv[x];
                sh_hjT_lo[d0 + x][row] = lv[x];
            }
        }

        // ---- adj codes for this lane's D-fragment positions (issued early) ----
        int adjv[4][4];   // [q][jt4], row = i0 + w*16 + g*4 + q, col = jt4*16 + c
#pragma unroll
        for (int q = 0; q < 4; ++q)
#pragma unroll
            for (int jt4 = 0; jt4 < 4; ++jt4)
                adjv[q][jt4] = adj[((size_t)b * kN + i0 + w * 16 + g * 4 + q) * kN
                                   + jt * TJ + jt4 * 16 + c];

        __syncthreads();   // sh_hj* ready

        // ---- e-phase: 4 k x 4 j-subtiles x 4 k-chunks of MFMA ----
        f32x4 E[4][4];     // [jt4][k]
#pragma unroll
        for (int jt4 = 0; jt4 < 4; ++jt4)
#pragma unroll
            for (int k = 0; k < 4; ++k) E[jt4][k] = (f32x4)0.f;

#pragma unroll
        for (int kc = 0; kc < 4; ++kc) {
#pragma unroll
            for (int jt4 = 0; jt4 < 4; ++jt4) {
                half8 bf = *reinterpret_cast<const half8*>(
                    &sh_hjh[jt4 * 16 + c][kc * 32 + g * 8]);
#pragma unroll
                for (int k = 0; k < 4; ++k)
                    E[jt4][k] = __builtin_amdgcn_mfma_f32_16x16x32_f16(
                        af[kc][k], bf, E[jt4][k], 0, 0, 0);
            }
        }

        // ---- select by adj, leaky_relu, online softmax; P -> fp16 in LDS ----
        float scq[4];
#pragma unroll
        for (int q = 0; q < 4; ++q) {
            float vvq[4];
#pragma unroll
            for (int jt4 = 0; jt4 < 4; ++jt4) {
                const int k = adjv[q][jt4];
                const float e = (k == 1) ? E[jt4][0][q]
                              : (k == 2) ? E[jt4][1][q]
                              : (k == 3) ? E[jt4][2][q]
                              :            E[jt4][3][q];
                const float lr = fmaxf(e, 0.f) + kAlpha * fminf(e, 0.f);
                vvq[jt4] = (k == 0) ? kNegInf : lr;
            }
            float rm = fmaxf(fmaxf(vvq[0], vvq[1]), fmaxf(vvq[2], vvq[3]));
            rm = fmaxf(rm, __shfl_xor(rm, 1));
            rm = fmaxf(rm, __shfl_xor(rm, 2));
            rm = fmaxf(rm, __shfl_xor(rm, 4));
            rm = fmaxf(rm, __shfl_xor(rm, 8));
            const float mnew = fmaxf(m_r[q], rm);
            const float sc = __expf(m_r[q] - mnew);
            half4v ph;
            float pqf[4];
#pragma unroll
            for (int jt4 = 0; jt4 < 4; ++jt4) {
                const float pv = __expf(vvq[jt4] - mnew);
                const _Float16 h = (_Float16)pv;   // fp16 P used by numerator
                ph[jt4]  = h;
                pqf[jt4] = (float)h;               // denominator from SAME values
            }
            float ps = (pqf[0] + pqf[1]) + (pqf[2] + pqf[3]);
            ps += __shfl_xor(ps, 1);
            ps += __shfl_xor(ps, 2);
            ps += __shfl_xor(ps, 4);
            ps += __shfl_xor(ps, 8);
            l_r[q] = l_r[q] * sc + ps;
            m_r[q] = mnew;
            scq[q] = sc;
            const int prow = w * 16 + g * 4 + q;   // wave-private row
#pragma unroll
            for (int jt4 = 0; jt4 < 4; ++jt4)
                sh_p16[prow][jt4 * 16 + c] = ph[jt4];
        }
        // NO barrier: PV A-frags read only this wave's sh_p16 rows; within-wave
        // LDS write->read ordering is enforced by the compiler's lgkmcnt waits.

        // ---- PV on MFMA: O = sc*O + P@hi + P@lo ----
        half8 pA0 = *reinterpret_cast<const half8*>(&sh_p16[w * 16 + c][g * 8]);
        half8 pA1 = *reinterpret_cast<const half8*>(&sh_p16[w * 16 + c][32 + g * 8]);
#pragma unroll
        for (int nt = 0; nt < 8; ++nt) {
            f32x4 acc = o_acc[nt];
            acc[0] *= scq[0]; acc[1] *= scq[1];
            acc[2] *= scq[2]; acc[3] *= scq[3];
            const int dd = nt * 16 + c;
            half8 bh0 = *reinterpret_cast<const half8*>(&sh_hjT_hi[dd][g * 8]);
            half8 bl0 = *reinterpret_cast<const half8*>(&sh_hjT_lo[dd][g * 8]);
            half8 bh1 = *reinterpret_cast<const half8*>(&sh_hjT_hi[dd][32 + g * 8]);
            half8 bl1 = *reinterpret_cast<const half8*>(&sh_hjT_lo[dd][32 + g * 8]);
            acc = __builtin_amdgcn_mfma_f32_16x16x32_f16(pA0, bh0, acc, 0, 0, 0);
            acc = __builtin_amdgcn_mfma_f32_16x16x32_f16(pA0, bl0, acc, 0, 0, 0);
            acc = __builtin_amdgcn_mfma_f32_16x16x32_f16(pA1, bh1, acc, 0, 0, 0);
            acc = __builtin_amdgcn_mfma_f32_16x16x32_f16(pA1, bl1, acc, 0, 0, 0);
            o_acc[nt] = acc;
        }
    }

    // ---- epilogue: divide by denom (in-register), scalar stores ----
    float inv[4];
#pragma unroll
    for (int q = 0; q < 4; ++q) inv[q] = 1.0f / l_r[q];
#pragma unroll
    for (int nt = 0; nt < 8; ++nt) {
#pragma unroll
        for (int q = 0; q < 4; ++q) {
            const int row = i0 + w * 16 + g * 4 + q;
            out[((size_t)b * kN + row) * kD + nt * 16 + c] = o_acc[nt][q] * inv[q];
        }
    }
}

extern "C" void kernel_launch(void* const* d_in, const int* in_sizes, int n_in,
                              void* d_out, int out_size, void* d_ws, size_t ws_size,
                              hipStream_t stream) {
    const float* hidden = (const float*)d_in[0];
    const int*   adj    = (const int*)d_in[1];
    const float* times  = (const float*)d_in[2];
    const float* a0 = (const float*)d_in[3];
    const float* a1 = (const float*)d_in[4];
    const float* a2 = (const float*)d_in[5];
    const float* a3 = (const float*)d_in[6];
    const float* p0 = (const float*)d_in[7];
    const float* p1 = (const float*)d_in[8];
    float* outp = (float*)d_out;
    (void)in_sizes; (void)n_in; (void)out_size; (void)d_ws; (void)ws_size;

    gat_mfma_full<<<dim3(kB * (kN / TI)), dim3(256), 0, stream>>>(
        hidden, adj, times, a0, a1, a2, a3, p0, p1, outp);
}